// Round 3
// baseline (282.619 us; speedup 1.0000x reference)
//
#include <hip/hip_runtime.h>
#include <hip/hip_bf16.h>

// Problem constants
#define BB 2
#define SS 2048
#define DD 1024
#define HH 16
#define DKK 64

typedef __attribute__((ext_vector_type(4))) float  f32x4;
typedef __attribute__((ext_vector_type(8))) short  s16x8;
typedef __attribute__((ext_vector_type(4))) short  s16x4;
typedef __attribute__((ext_vector_type(4))) float  fvec4;

__device__ __forceinline__ short f2bs(float f) {
    union { __hip_bfloat16 b; short s; } u;
    u.b = __float2bfloat16(f);
    return u.s;
}

__device__ __forceinline__ void gload_lds16(const short* g, short* l) {
    __builtin_amdgcn_global_load_lds((const __attribute__((address_space(1))) void*)g,
                                     (__attribute__((address_space(3))) void*)l, 16, 0, 0);
}

// ---------------------------------------------------------------------------
// fp32 -> bf16 convert, 7 tensors in one launch (blockIdx.y selects tensor)
// ---------------------------------------------------------------------------
__global__ __launch_bounds__(256) void cvt_all(
    const float* __restrict__ q,  const float* __restrict__ k,  const float* __restrict__ v,
    const float* __restrict__ wq, const float* __restrict__ wk, const float* __restrict__ wv,
    const float* __restrict__ wo,
    short* __restrict__ qo,  short* __restrict__ ko,  short* __restrict__ vo,
    short* __restrict__ wqo, short* __restrict__ wko, short* __restrict__ wvo,
    short* __restrict__ woo)
{
    const float* src; short* dst; int n;
    switch (blockIdx.y) {
        case 0: src = q;  dst = qo;  n = BB * SS * DD; break;
        case 1: src = k;  dst = ko;  n = BB * SS * DD; break;
        case 2: src = v;  dst = vo;  n = BB * SS * DD; break;
        case 3: src = wq; dst = wqo; n = DD * DD; break;
        case 4: src = wk; dst = wko; n = DD * DD; break;
        case 5: src = wv; dst = wvo; n = DD * DD; break;
        default: src = wo; dst = woo; n = DD * DD; break;
    }
    int i = (blockIdx.x * 256 + threadIdx.x) * 8;
    const int stride = gridDim.x * 256 * 8;
    for (; i < n; i += stride) {
        fvec4 a = *(const fvec4*)&src[i];
        fvec4 b = *(const fvec4*)&src[i + 4];
        s16x8 o;
        o[0] = f2bs(a[0]); o[1] = f2bs(a[1]); o[2] = f2bs(a[2]); o[3] = f2bs(a[3]);
        o[4] = f2bs(b[0]); o[5] = f2bs(b[1]); o[6] = f2bs(b[2]); o[7] = f2bs(b[3]);
        *(s16x8*)&dst[i] = o;
    }
}

// ---------------------------------------------------------------------------
// GEMM (NT), bf16 A and B: C[M,N] = (A[M,K] * Bw[N,K]^T + bias) * oscale
// m97 structure: global_load_lds(16B) staging, 2-barrier K-loop, BK=32.
// BN=128: 4 waves 2x2, wave 64x64 (QKV, fused 3 tensors via blockIdx.z).
// BN=64 : 4 waves 4x1, wave 32x64 (O-proj; more blocks for occupancy).
// ---------------------------------------------------------------------------
template<int BN, bool OUTF32>
__global__ __launch_bounds__(256) void gemm_nt_bf16(
    const short* __restrict__ A0, const short* __restrict__ A1, const short* __restrict__ A2,
    const short* __restrict__ B0, const short* __restrict__ B1, const short* __restrict__ B2,
    const float* __restrict__ c0, const float* __restrict__ c1, const float* __restrict__ c2,
    void* __restrict__ O0, void* __restrict__ O1, void* __restrict__ O2,
    float os0, float os1, float os2, int M, int N, int K)
{
    const int z = blockIdx.z;
    const short* A    = z == 0 ? A0 : (z == 1 ? A1 : A2);
    const short* Bw   = z == 0 ? B0 : (z == 1 ? B1 : B2);
    const float* bias = z == 0 ? c0 : (z == 1 ? c1 : c2);
    void* Cp          = z == 0 ? O0 : (z == 1 ? O1 : O2);
    const float oscale = z == 0 ? os0 : (z == 1 ? os1 : os2);

    __shared__ short As[128][32];
    __shared__ short Bs[BN][32];

    const int tid  = threadIdx.x;
    const int lane = tid & 63;
    const int wid  = tid >> 6;
    const int r16  = lane & 15;
    const int g    = lane >> 4;
    const int m0   = blockIdx.y * 128;
    const int n0   = blockIdx.x * BN;
    constexpr int MR = (BN == 128) ? 4 : 2;
    constexpr int NR = 4;
    const int wr = (BN == 128) ? (wid >> 1) * 64 : wid * 32;
    const int wc = (BN == 128) ? (wid & 1) * 64 : 0;
    const int lrow = lane >> 2;          // 0..15, row within 16-row stripe
    const int lch  = (lane & 3) * 8;     // 8-elem col chunk

    f32x4 acc[MR][NR];
#pragma unroll
    for (int mi = 0; mi < MR; ++mi)
#pragma unroll
        for (int ni = 0; ni < NR; ++ni) acc[mi][ni] = (f32x4){0.f, 0.f, 0.f, 0.f};

    const int nk = K >> 5;
#pragma unroll 1
    for (int kt = 0; kt < nk; ++kt) {
        const int k0 = kt * 32;
        if (kt) __syncthreads();
        // --- stage A (128x32): wave w covers rows [32w, 32w+32), 2 instrs ---
        {
            const short* ga = &A[(size_t)(m0 + wid * 32 + lrow) * K + k0 + lch];
            gload_lds16(ga, &As[wid * 32][0]);
            gload_lds16(ga + (size_t)16 * K, &As[wid * 32 + 16][0]);
        }
        // --- stage B ---
        if constexpr (BN == 128) {
            const short* gb = &Bw[(size_t)(n0 + wid * 32 + lrow) * K + k0 + lch];
            gload_lds16(gb, &Bs[wid * 32][0]);
            gload_lds16(gb + (size_t)16 * K, &Bs[wid * 32 + 16][0]);
        } else {
            const short* gb = &Bw[(size_t)(n0 + wid * 16 + lrow) * K + k0 + lch];
            gload_lds16(gb, &Bs[wid * 16][0]);
        }
        __syncthreads();   // drains vmcnt (compiler emits full waitcnt before barrier)

        s16x8 af[MR], bf[NR];
#pragma unroll
        for (int mi = 0; mi < MR; ++mi)
            af[mi] = *(const s16x8*)&As[wr + mi * 16 + r16][g * 8];
#pragma unroll
        for (int ni = 0; ni < NR; ++ni)
            bf[ni] = *(const s16x8*)&Bs[wc + ni * 16 + r16][g * 8];
#pragma unroll
        for (int mi = 0; mi < MR; ++mi)
#pragma unroll
            for (int ni = 0; ni < NR; ++ni)
                acc[mi][ni] = __builtin_amdgcn_mfma_f32_16x16x32_bf16(
                    af[mi], bf[ni], acc[mi][ni], 0, 0, 0);
    }

    // epilogue: (acc + bias) * oscale; C/D: col = l&15, row = (l>>4)*4 + r
#pragma unroll
    for (int ni = 0; ni < NR; ++ni) {
        const int col = n0 + wc + ni * 16 + r16;
        const float bv = bias[col];
#pragma unroll
        for (int mi = 0; mi < MR; ++mi) {
#pragma unroll
            for (int r = 0; r < 4; ++r) {
                const int row = m0 + wr + mi * 16 + g * 4 + r;
                const float vv = (acc[mi][ni][r] + bv) * oscale;
                if constexpr (OUTF32)
                    ((float*)Cp)[(size_t)row * N + col] = vv;
                else
                    ((short*)Cp)[(size_t)row * N + col] = f2bs(vv);
            }
        }
    }
}

// ---------------------------------------------------------------------------
// Per-head V transpose: vp (head-major [bh][s][dk]) -> vT ([bh][dk][s])
// ---------------------------------------------------------------------------
__global__ __launch_bounds__(256) void mha_transpose_v(
    const short* __restrict__ vp, short* __restrict__ vT)
{
    const int st = blockIdx.x;
    const int bh = blockIdx.y;
    const short* src = vp + (size_t)bh * SS * DKK;
    short*       dst = vT + (size_t)bh * SS * DKK;
    const int tid = threadIdx.x;
#pragma unroll
    for (int i = 0; i < 2; ++i) {
        const int c  = tid + i * 256;   // 0..511
        const int dk = c >> 3;          // 0..63
        const int sc = c & 7;           // 0..7
        const int s0 = st * 64 + sc * 8;
        s16x8 v;
#pragma unroll
        for (int j = 0; j < 8; ++j) v[j] = src[(size_t)(s0 + j) * DKK + dk];
        *(s16x8*)&dst[(size_t)dk * SS + s0] = v;
    }
}

// ---------------------------------------------------------------------------
// Flash attention (causal), buggy-reshape head layout.
// 1024 blocks (4/CU -> 4 waves/SIMD), XCD-aware decode: 4 heads per XCD so
// each head's K/V (512KB) stays L2-resident on one XCD.
// Intra-block balance: waves 0-1 take rows [32bx,32bx+32), waves 2-3 take
// [2016-32bx, 2048-32bx) -> exactly 66 k-tiles per block for every bx.
// Softmax-lite (pre-scaled scores, no max), register prefetch of K/V frags.
// ---------------------------------------------------------------------------
__global__ __launch_bounds__(256, 4) void mha_attn(
    const short* __restrict__ qp, const short* __restrict__ kp,
    const short* __restrict__ vT, short* __restrict__ ctx)
{
    __shared__ short P[4][16][72];   // per-wave [16 rows][64 keys]

    const int tid  = threadIdx.x;
    const int wid  = tid >> 6;
    const int lane = tid & 63;
    const int r16  = lane & 15;
    const int g    = lane >> 4;

    // XCD-aware decode of 1024 linear blocks
    const int lin  = blockIdx.x;
    const int xcd  = lin & 7;
    const int rest = lin >> 3;            // 0..127
    const int bh   = (xcd << 2) | (rest & 3);   // 0..31, 4 heads per XCD
    const int bx   = rest >> 2;           // 0..31
    const int b    = bh >> 4;
    const int h    = bh & 15;

    const short* Qh = qp + (size_t)bh * SS * DKK;
    const short* Kh = kp + (size_t)bh * SS * DKK;
    const short* Vh = vT + (size_t)bh * SS * DKK;   // [DK][S]

    // per-wave 16-row block; waves 0/1 low pair-half, waves 2/3 high half
    const int qr0 = (wid < 2) ? (32 * bx + 16 * wid) : (2016 - 32 * bx + 16 * (wid - 2));
    const int nkt = (qr0 >> 6) + 1;
    const int jd  = qr0 >> 6;   // diagonal k-tile index

    const s16x8 qf0 = *(const s16x8*)&Qh[(size_t)(qr0 + r16) * DKK + g * 8];
    const s16x8 qf1 = *(const s16x8*)&Qh[(size_t)(qr0 + r16) * DKK + 32 + g * 8];

    f32x4 po[4];
#pragma unroll
    for (int i = 0; i < 4; ++i) po[i] = (f32x4){0.f, 0.f, 0.f, 0.f};
    float l_[4] = {0.f, 0.f, 0.f, 0.f};

    // prologue: K and V fragments for k-tile 0
    s16x8 kc[8], vf[8];
#pragma unroll
    for (int cg = 0; cg < 4; ++cg) {
        kc[2 * cg]     = *(const s16x8*)&Kh[(size_t)(cg * 16 + r16) * DKK + g * 8];
        kc[2 * cg + 1] = *(const s16x8*)&Kh[(size_t)(cg * 16 + r16) * DKK + 32 + g * 8];
    }
#pragma unroll
    for (int dg = 0; dg < 4; ++dg) {
        vf[2 * dg]     = *(const s16x8*)&Vh[(size_t)(dg * 16 + r16) * SS + g * 8];
        vf[2 * dg + 1] = *(const s16x8*)&Vh[(size_t)(dg * 16 + r16) * SS + 32 + g * 8];
    }

#pragma unroll 1
    for (int j = 0; j < nkt; ++j) {
        const int k0 = j * 64;
        // ---- QK^T (scores pre-scaled via Q GEMM epilogue) ----
        f32x4 sc[4];
        __builtin_amdgcn_s_setprio(1);
#pragma unroll
        for (int cg = 0; cg < 4; ++cg) {
            f32x4 tt = (f32x4){0.f, 0.f, 0.f, 0.f};
            tt = __builtin_amdgcn_mfma_f32_16x16x32_bf16(qf0, kc[2 * cg], tt, 0, 0, 0);
            tt = __builtin_amdgcn_mfma_f32_16x16x32_bf16(qf1, kc[2 * cg + 1], tt, 0, 0, 0);
            sc[cg] = tt;
        }
        __builtin_amdgcn_s_setprio(0);
        const bool has = (j + 1 < nkt);
        // ---- prefetch next K tile (consumed next iteration) ----
        s16x8 kn[8];
        if (has) {
            const int k1 = k0 + 64;
#pragma unroll
            for (int cg = 0; cg < 4; ++cg) {
                kn[2 * cg]     = *(const s16x8*)&Kh[(size_t)(k1 + cg * 16 + r16) * DKK + g * 8];
                kn[2 * cg + 1] = *(const s16x8*)&Kh[(size_t)(k1 + cg * 16 + r16) * DKK + 32 + g * 8];
            }
        }
        // ---- causal mask (diag tile only) ----
        if (j == jd) {
#pragma unroll
            for (int cg = 0; cg < 4; ++cg)
#pragma unroll
                for (int r = 0; r < 4; ++r)
                    if (k0 + cg * 16 + r16 > qr0 + g * 4 + r) sc[cg][r] = -1e9f;
        }
        // ---- softmax-lite: exp + per-lane partial sums + P write ----
#pragma unroll
        for (int cg = 0; cg < 4; ++cg)
#pragma unroll
            for (int r = 0; r < 4; ++r) {
                const float p = __expf(sc[cg][r]);
                l_[r] += p;
                P[wid][g * 4 + r][cg * 16 + r16] = f2bs(p);
            }
        // same-wave write->read: compiler inserts lgkmcnt wait
        const s16x8 pf0 = *(const s16x8*)&P[wid][r16][g * 8];
        const s16x8 pf1 = *(const s16x8*)&P[wid][r16][32 + g * 8];
        // ---- PV ----
        __builtin_amdgcn_s_setprio(1);
#pragma unroll
        for (int dg = 0; dg < 4; ++dg) {
            po[dg] = __builtin_amdgcn_mfma_f32_16x16x32_bf16(pf0, vf[2 * dg], po[dg], 0, 0, 0);
            po[dg] = __builtin_amdgcn_mfma_f32_16x16x32_bf16(pf1, vf[2 * dg + 1], po[dg], 0, 0, 0);
        }
        __builtin_amdgcn_s_setprio(0);
        // ---- prefetch next V tile; rotate K ----
        if (has) {
            const int k1 = k0 + 64;
#pragma unroll
            for (int dg = 0; dg < 4; ++dg) {
                vf[2 * dg]     = *(const s16x8*)&Vh[(size_t)(dg * 16 + r16) * SS + k1 + g * 8];
                vf[2 * dg + 1] = *(const s16x8*)&Vh[(size_t)(dg * 16 + r16) * SS + k1 + 32 + g * 8];
            }
#pragma unroll
            for (int i = 0; i < 8; ++i) kc[i] = kn[i];
        }
    }

    // ---- epilogue: reduce row sums across 16 lanes, normalize, store ----
#pragma unroll
    for (int r = 0; r < 4; ++r) {
#pragma unroll
        for (int off = 1; off < 16; off <<= 1)
            l_[r] += __shfl_xor(l_[r], off);
    }
#pragma unroll
    for (int dg = 0; dg < 4; ++dg)
#pragma unroll
        for (int r = 0; r < 4; ++r) {
            const int srow = qr0 + g * 4 + r;
            const float v = po[dg][r] * __builtin_amdgcn_rcpf(l_[r]);
            ctx[((size_t)(b * SS + srow)) * DD + h * 64 + dg * 16 + r16] = f2bs(v);
        }
}

// ---------------------------------------------------------------------------
extern "C" void kernel_launch(void* const* d_in, const int* in_sizes, int n_in,
                              void* d_out, int out_size, void* d_ws, size_t ws_size,
                              hipStream_t stream) {
    const float* query = (const float*)d_in[0];
    const float* key   = (const float*)d_in[1];
    const float* value = (const float*)d_in[2];
    // d_in[3] = mask (causal tril) -- implemented analytically
    const float* Wq = (const float*)d_in[4];
    const float* bq = (const float*)d_in[5];
    const float* Wk = (const float*)d_in[6];
    const float* bk = (const float*)d_in[7];
    const float* Wv = (const float*)d_in[8];
    const float* bv = (const float*)d_in[9];
    const float* Wo = (const float*)d_in[10];
    const float* bo = (const float*)d_in[11];
    float* out = (float*)d_out;

    const size_t elems = (size_t)BB * SS * DD;   // 4M
    const size_t wel   = (size_t)DD * DD;        // 1M
    short* qx  = (short*)d_ws;        // bf16 inputs
    short* kx  = qx + elems;
    short* vx  = kx + elems;
    short* wqx = vx + elems;          // bf16 weights
    short* wkx = wqx + wel;
    short* wvx = wkx + wel;
    short* wox = wvx + wel;
    short* qp  = wox + wel;           // projections
    short* kp  = qp + elems;
    short* vp  = kp + elems;
    short* vT  = qx;                  // qx dead after QKV GEMM launch
    short* ctx = kx;                  // kx dead after QKV GEMM launch

    const int M = BB * SS;   // 4096

    // 1) convert everything to bf16
    cvt_all<<<dim3(1024, 7), 256, 0, stream>>>(query, key, value, Wq, Wk, Wv, Wo,
                                               qx, kx, vx, wqx, wkx, wvx, wox);
    // 2) fused Q/K/V projections (768 blocks = 3/CU); 1/sqrt(DK) folded into Q
    gemm_nt_bf16<128, false><<<dim3(DD / 128, M / 128, 3), 256, 0, stream>>>(
        qx, kx, vx, wqx, wkx, wvx, bq, bk, bv, qp, kp, vp,
        0.125f, 1.0f, 1.0f, M, DD, DD);
    // 3) V transpose per head
    mha_transpose_v<<<dim3(SS / 64, BB * HH), 256, 0, stream>>>(vp, vT);
    // 4) attention
    mha_attn<<<dim3(1024), 256, 0, stream>>>(qp, kp, vT, ctx);
    // 5) output projection (512 blocks = 2/CU)
    gemm_nt_bf16<64, true><<<dim3(DD / 64, M / 128, 1), 256, 0, stream>>>(
        ctx, ctx, ctx, wox, wox, wox, bo, bo, bo, out, out, out,
        1.0f, 1.0f, 1.0f, M, DD, DD);
}

// Round 4
// 231.336 us; speedup vs baseline: 1.2217x; 1.2217x over previous
//
#include <hip/hip_runtime.h>
#include <hip/hip_bf16.h>

// Problem constants
#define BB 2
#define SS 2048
#define DD 1024
#define HH 16
#define DKK 64

typedef __attribute__((ext_vector_type(4))) float  f32x4;
typedef __attribute__((ext_vector_type(8))) short  s16x8;
typedef __attribute__((ext_vector_type(4))) short  s16x4;
typedef __attribute__((ext_vector_type(4))) float  fvec4;

__device__ __forceinline__ short f2bs(float f) {
    union { __hip_bfloat16 b; short s; } u;
    u.b = __float2bfloat16(f);
    return u.s;
}

__device__ __forceinline__ void gload_lds16(const short* g, short* l) {
    __builtin_amdgcn_global_load_lds((const __attribute__((address_space(1))) void*)g,
                                     (__attribute__((address_space(3))) void*)l, 16, 0, 0);
}

// ---------------------------------------------------------------------------
// fp32 -> bf16 convert, 7 tensors in one launch (blockIdx.y selects tensor)
// ---------------------------------------------------------------------------
__global__ __launch_bounds__(256) void cvt_all(
    const float* __restrict__ q,  const float* __restrict__ k,  const float* __restrict__ v,
    const float* __restrict__ wq, const float* __restrict__ wk, const float* __restrict__ wv,
    const float* __restrict__ wo,
    short* __restrict__ qo,  short* __restrict__ ko,  short* __restrict__ vo,
    short* __restrict__ wqo, short* __restrict__ wko, short* __restrict__ wvo,
    short* __restrict__ woo)
{
    const float* src; short* dst; int n;
    switch (blockIdx.y) {
        case 0: src = q;  dst = qo;  n = BB * SS * DD; break;
        case 1: src = k;  dst = ko;  n = BB * SS * DD; break;
        case 2: src = v;  dst = vo;  n = BB * SS * DD; break;
        case 3: src = wq; dst = wqo; n = DD * DD; break;
        case 4: src = wk; dst = wko; n = DD * DD; break;
        case 5: src = wv; dst = wvo; n = DD * DD; break;
        default: src = wo; dst = woo; n = DD * DD; break;
    }
    int i = (blockIdx.x * 256 + threadIdx.x) * 8;
    const int stride = gridDim.x * 256 * 8;
    for (; i < n; i += stride) {
        fvec4 a = *(const fvec4*)&src[i];
        fvec4 b = *(const fvec4*)&src[i + 4];
        s16x8 o;
        o[0] = f2bs(a[0]); o[1] = f2bs(a[1]); o[2] = f2bs(a[2]); o[3] = f2bs(a[3]);
        o[4] = f2bs(b[0]); o[5] = f2bs(b[1]); o[6] = f2bs(b[2]); o[7] = f2bs(b[3]);
        *(s16x8*)&dst[i] = o;
    }
}

// ---------------------------------------------------------------------------
// GEMM (NT), bf16 A and B: C[M,N] = (A[M,K] * Bw[N,K]^T + bias) * oscale
// m97 structure: global_load_lds(16B) staging, 2-barrier K-loop, BK=32.
// BN=128: 4 waves 2x2, wave 64x64 (QKV, fused 3 tensors via blockIdx.z).
// BN=64 : 4 waves 4x1, wave 32x64 (O-proj; more blocks for occupancy).
// ---------------------------------------------------------------------------
template<int BN, bool OUTF32>
__global__ __launch_bounds__(256) void gemm_nt_bf16(
    const short* __restrict__ A0, const short* __restrict__ A1, const short* __restrict__ A2,
    const short* __restrict__ B0, const short* __restrict__ B1, const short* __restrict__ B2,
    const float* __restrict__ c0, const float* __restrict__ c1, const float* __restrict__ c2,
    void* __restrict__ O0, void* __restrict__ O1, void* __restrict__ O2,
    float os0, float os1, float os2, int M, int N, int K)
{
    const int z = blockIdx.z;
    const short* A    = z == 0 ? A0 : (z == 1 ? A1 : A2);
    const short* Bw   = z == 0 ? B0 : (z == 1 ? B1 : B2);
    const float* bias = z == 0 ? c0 : (z == 1 ? c1 : c2);
    void* Cp          = z == 0 ? O0 : (z == 1 ? O1 : O2);
    const float oscale = z == 0 ? os0 : (z == 1 ? os1 : os2);

    __shared__ short As[128][32];
    __shared__ short Bs[BN][32];

    const int tid  = threadIdx.x;
    const int lane = tid & 63;
    const int wid  = tid >> 6;
    const int r16  = lane & 15;
    const int g    = lane >> 4;
    const int m0   = blockIdx.y * 128;
    const int n0   = blockIdx.x * BN;
    constexpr int MR = (BN == 128) ? 4 : 2;
    constexpr int NR = 4;
    const int wr = (BN == 128) ? (wid >> 1) * 64 : wid * 32;
    const int wc = (BN == 128) ? (wid & 1) * 64 : 0;
    const int lrow = lane >> 2;          // 0..15, row within 16-row stripe
    const int lch  = (lane & 3) * 8;     // 8-elem col chunk

    f32x4 acc[MR][NR];
#pragma unroll
    for (int mi = 0; mi < MR; ++mi)
#pragma unroll
        for (int ni = 0; ni < NR; ++ni) acc[mi][ni] = (f32x4){0.f, 0.f, 0.f, 0.f};

    const int nk = K >> 5;
#pragma unroll 1
    for (int kt = 0; kt < nk; ++kt) {
        const int k0 = kt * 32;
        if (kt) __syncthreads();
        // --- stage A (128x32): wave w covers rows [32w, 32w+32), 2 instrs ---
        {
            const short* ga = &A[(size_t)(m0 + wid * 32 + lrow) * K + k0 + lch];
            gload_lds16(ga, &As[wid * 32][0]);
            gload_lds16(ga + (size_t)16 * K, &As[wid * 32 + 16][0]);
        }
        // --- stage B ---
        if constexpr (BN == 128) {
            const short* gb = &Bw[(size_t)(n0 + wid * 32 + lrow) * K + k0 + lch];
            gload_lds16(gb, &Bs[wid * 32][0]);
            gload_lds16(gb + (size_t)16 * K, &Bs[wid * 32 + 16][0]);
        } else {
            const short* gb = &Bw[(size_t)(n0 + wid * 16 + lrow) * K + k0 + lch];
            gload_lds16(gb, &Bs[wid * 16][0]);
        }
        __syncthreads();   // drains vmcnt (compiler emits full waitcnt before barrier)

        s16x8 af[MR], bf[NR];
#pragma unroll
        for (int mi = 0; mi < MR; ++mi)
            af[mi] = *(const s16x8*)&As[wr + mi * 16 + r16][g * 8];
#pragma unroll
        for (int ni = 0; ni < NR; ++ni)
            bf[ni] = *(const s16x8*)&Bs[wc + ni * 16 + r16][g * 8];
#pragma unroll
        for (int mi = 0; mi < MR; ++mi)
#pragma unroll
            for (int ni = 0; ni < NR; ++ni)
                acc[mi][ni] = __builtin_amdgcn_mfma_f32_16x16x32_bf16(
                    af[mi], bf[ni], acc[mi][ni], 0, 0, 0);
    }

    // epilogue: (acc + bias) * oscale; C/D: col = l&15, row = (l>>4)*4 + r
#pragma unroll
    for (int ni = 0; ni < NR; ++ni) {
        const int col = n0 + wc + ni * 16 + r16;
        const float bv = bias[col];
#pragma unroll
        for (int mi = 0; mi < MR; ++mi) {
#pragma unroll
            for (int r = 0; r < 4; ++r) {
                const int row = m0 + wr + mi * 16 + g * 4 + r;
                const float vv = (acc[mi][ni][r] + bv) * oscale;
                if constexpr (OUTF32)
                    ((float*)Cp)[(size_t)row * N + col] = vv;
                else
                    ((short*)Cp)[(size_t)row * N + col] = f2bs(vv);
            }
        }
    }
}

// ---------------------------------------------------------------------------
// Per-head V transpose: vp (head-major [bh][s][dk]) -> vT ([bh][dk][s])
// ---------------------------------------------------------------------------
__global__ __launch_bounds__(256) void mha_transpose_v(
    const short* __restrict__ vp, short* __restrict__ vT)
{
    const int st = blockIdx.x;
    const int bh = blockIdx.y;
    const short* src = vp + (size_t)bh * SS * DKK;
    short*       dst = vT + (size_t)bh * SS * DKK;
    const int tid = threadIdx.x;
#pragma unroll
    for (int i = 0; i < 2; ++i) {
        const int c  = tid + i * 256;   // 0..511
        const int dk = c >> 3;          // 0..63
        const int sc = c & 7;           // 0..7
        const int s0 = st * 64 + sc * 8;
        s16x8 v;
#pragma unroll
        for (int j = 0; j < 8; ++j) v[j] = src[(size_t)(s0 + j) * DKK + dk];
        *(s16x8*)&dst[(size_t)dk * SS + s0] = v;
    }
}

// ---------------------------------------------------------------------------
// Flash attention (causal), buggy-reshape head layout.
// 1024 blocks, XCD-aware decode: 4 heads per XCD so each head's K/V (512KB)
// stays L2-resident on one XCD.
// Intra-block balance: waves 0-1 take rows [32bx,32bx+32), waves 2-3 take
// [2016-32bx, 2048-32bx) -> exactly 66 k-tiles per block for every bx.
// launch_bounds(256,2): VGPR budget ~100-128 (no spill; <=128 already gives
// 4 waves/SIMD per m69 quantum) -> 4 blocks/CU co-resident with 1024 blocks.
// Softmax-lite (pre-scaled scores, no max), register prefetch of K/V frags.
// ---------------------------------------------------------------------------
__global__ __launch_bounds__(256, 2) void mha_attn(
    const short* __restrict__ qp, const short* __restrict__ kp,
    const short* __restrict__ vT, short* __restrict__ ctx)
{
    __shared__ short P[4][16][72];   // per-wave [16 rows][64 keys]

    const int tid  = threadIdx.x;
    const int wid  = tid >> 6;
    const int lane = tid & 63;
    const int r16  = lane & 15;
    const int g    = lane >> 4;

    // XCD-aware decode of 1024 linear blocks
    const int lin  = blockIdx.x;
    const int xcd  = lin & 7;
    const int rest = lin >> 3;            // 0..127
    const int bh   = (xcd << 2) | (rest & 3);   // 0..31, 4 heads per XCD
    const int bx   = rest >> 2;           // 0..31
    const int b    = bh >> 4;
    const int h    = bh & 15;

    const short* Qh = qp + (size_t)bh * SS * DKK;
    const short* Kh = kp + (size_t)bh * SS * DKK;
    const short* Vh = vT + (size_t)bh * SS * DKK;   // [DK][S]

    // per-wave 16-row block; waves 0/1 low pair-half, waves 2/3 high half
    const int qr0 = (wid < 2) ? (32 * bx + 16 * wid) : (2016 - 32 * bx + 16 * (wid - 2));
    const int nkt = (qr0 >> 6) + 1;
    const int jd  = qr0 >> 6;   // diagonal k-tile index

    const s16x8 qf0 = *(const s16x8*)&Qh[(size_t)(qr0 + r16) * DKK + g * 8];
    const s16x8 qf1 = *(const s16x8*)&Qh[(size_t)(qr0 + r16) * DKK + 32 + g * 8];

    f32x4 po[4];
#pragma unroll
    for (int i = 0; i < 4; ++i) po[i] = (f32x4){0.f, 0.f, 0.f, 0.f};
    float l_[4] = {0.f, 0.f, 0.f, 0.f};

    // prologue: K and V fragments for k-tile 0
    s16x8 kc[8], vf[8];
#pragma unroll
    for (int cg = 0; cg < 4; ++cg) {
        kc[2 * cg]     = *(const s16x8*)&Kh[(size_t)(cg * 16 + r16) * DKK + g * 8];
        kc[2 * cg + 1] = *(const s16x8*)&Kh[(size_t)(cg * 16 + r16) * DKK + 32 + g * 8];
    }
#pragma unroll
    for (int dg = 0; dg < 4; ++dg) {
        vf[2 * dg]     = *(const s16x8*)&Vh[(size_t)(dg * 16 + r16) * SS + g * 8];
        vf[2 * dg + 1] = *(const s16x8*)&Vh[(size_t)(dg * 16 + r16) * SS + 32 + g * 8];
    }

#pragma unroll 1
    for (int j = 0; j < nkt; ++j) {
        const int k0 = j * 64;
        // ---- QK^T (scores pre-scaled via Q GEMM epilogue) ----
        f32x4 sc[4];
        __builtin_amdgcn_s_setprio(1);
#pragma unroll
        for (int cg = 0; cg < 4; ++cg) {
            f32x4 tt = (f32x4){0.f, 0.f, 0.f, 0.f};
            tt = __builtin_amdgcn_mfma_f32_16x16x32_bf16(qf0, kc[2 * cg], tt, 0, 0, 0);
            tt = __builtin_amdgcn_mfma_f32_16x16x32_bf16(qf1, kc[2 * cg + 1], tt, 0, 0, 0);
            sc[cg] = tt;
        }
        __builtin_amdgcn_s_setprio(0);
        const bool has = (j + 1 < nkt);
        // ---- prefetch next K tile (consumed next iteration) ----
        s16x8 kn[8];
        if (has) {
            const int k1 = k0 + 64;
#pragma unroll
            for (int cg = 0; cg < 4; ++cg) {
                kn[2 * cg]     = *(const s16x8*)&Kh[(size_t)(k1 + cg * 16 + r16) * DKK + g * 8];
                kn[2 * cg + 1] = *(const s16x8*)&Kh[(size_t)(k1 + cg * 16 + r16) * DKK + 32 + g * 8];
            }
        }
        // ---- causal mask (diag tile only) ----
        if (j == jd) {
#pragma unroll
            for (int cg = 0; cg < 4; ++cg)
#pragma unroll
                for (int r = 0; r < 4; ++r)
                    if (k0 + cg * 16 + r16 > qr0 + g * 4 + r) sc[cg][r] = -1e9f;
        }
        // ---- softmax-lite: exp + per-lane partial sums + P write ----
#pragma unroll
        for (int cg = 0; cg < 4; ++cg)
#pragma unroll
            for (int r = 0; r < 4; ++r) {
                const float p = __expf(sc[cg][r]);
                l_[r] += p;
                P[wid][g * 4 + r][cg * 16 + r16] = f2bs(p);
            }
        // same-wave write->read: compiler inserts lgkmcnt wait
        const s16x8 pf0 = *(const s16x8*)&P[wid][r16][g * 8];
        const s16x8 pf1 = *(const s16x8*)&P[wid][r16][32 + g * 8];
        // ---- PV ----
        __builtin_amdgcn_s_setprio(1);
#pragma unroll
        for (int dg = 0; dg < 4; ++dg) {
            po[dg] = __builtin_amdgcn_mfma_f32_16x16x32_bf16(pf0, vf[2 * dg], po[dg], 0, 0, 0);
            po[dg] = __builtin_amdgcn_mfma_f32_16x16x32_bf16(pf1, vf[2 * dg + 1], po[dg], 0, 0, 0);
        }
        __builtin_amdgcn_s_setprio(0);
        // ---- prefetch next V tile; rotate K ----
        if (has) {
            const int k1 = k0 + 64;
#pragma unroll
            for (int dg = 0; dg < 4; ++dg) {
                vf[2 * dg]     = *(const s16x8*)&Vh[(size_t)(dg * 16 + r16) * SS + k1 + g * 8];
                vf[2 * dg + 1] = *(const s16x8*)&Vh[(size_t)(dg * 16 + r16) * SS + k1 + 32 + g * 8];
            }
#pragma unroll
            for (int i = 0; i < 8; ++i) kc[i] = kn[i];
        }
    }

    // ---- epilogue: reduce row sums across 16 lanes, normalize, store ----
#pragma unroll
    for (int r = 0; r < 4; ++r) {
#pragma unroll
        for (int off = 1; off < 16; off <<= 1)
            l_[r] += __shfl_xor(l_[r], off);
    }
#pragma unroll
    for (int dg = 0; dg < 4; ++dg)
#pragma unroll
        for (int r = 0; r < 4; ++r) {
            const int srow = qr0 + g * 4 + r;
            const float v = po[dg][r] * __builtin_amdgcn_rcpf(l_[r]);
            ctx[((size_t)(b * SS + srow)) * DD + h * 64 + dg * 16 + r16] = f2bs(v);
        }
}

// ---------------------------------------------------------------------------
extern "C" void kernel_launch(void* const* d_in, const int* in_sizes, int n_in,
                              void* d_out, int out_size, void* d_ws, size_t ws_size,
                              hipStream_t stream) {
    const float* query = (const float*)d_in[0];
    const float* key   = (const float*)d_in[1];
    const float* value = (const float*)d_in[2];
    // d_in[3] = mask (causal tril) -- implemented analytically
    const float* Wq = (const float*)d_in[4];
    const float* bq = (const float*)d_in[5];
    const float* Wk = (const float*)d_in[6];
    const float* bk = (const float*)d_in[7];
    const float* Wv = (const float*)d_in[8];
    const float* bv = (const float*)d_in[9];
    const float* Wo = (const float*)d_in[10];
    const float* bo = (const float*)d_in[11];
    float* out = (float*)d_out;

    const size_t elems = (size_t)BB * SS * DD;   // 4M
    const size_t wel   = (size_t)DD * DD;        // 1M
    short* qx  = (short*)d_ws;        // bf16 inputs
    short* kx  = qx + elems;
    short* vx  = kx + elems;
    short* wqx = vx + elems;          // bf16 weights
    short* wkx = wqx + wel;
    short* wvx = wkx + wel;
    short* wox = wvx + wel;
    short* qp  = wox + wel;           // projections
    short* kp  = qp + elems;
    short* vp  = kp + elems;
    short* vT  = qx;                  // qx dead after QKV GEMM launch
    short* ctx = kx;                  // kx dead after QKV GEMM launch

    const int M = BB * SS;   // 4096

    // 1) convert everything to bf16
    cvt_all<<<dim3(1024, 7), 256, 0, stream>>>(query, key, value, Wq, Wk, Wv, Wo,
                                               qx, kx, vx, wqx, wkx, wvx, wox);
    // 2) fused Q/K/V projections (768 blocks = 3/CU); 1/sqrt(DK) folded into Q
    gemm_nt_bf16<128, false><<<dim3(DD / 128, M / 128, 3), 256, 0, stream>>>(
        qx, kx, vx, wqx, wkx, wvx, bq, bk, bv, qp, kp, vp,
        0.125f, 1.0f, 1.0f, M, DD, DD);
    // 3) V transpose per head
    mha_transpose_v<<<dim3(SS / 64, BB * HH), 256, 0, stream>>>(vp, vT);
    // 4) attention
    mha_attn<<<dim3(1024), 256, 0, stream>>>(qp, kp, vT, ctx);
    // 5) output projection (512 blocks = 2/CU)
    gemm_nt_bf16<64, true><<<dim3(DD / 64, M / 128, 1), 256, 0, stream>>>(
        ctx, ctx, ctx, wox, wox, wox, bo, bo, bo, out, out, out,
        1.0f, 1.0f, 1.0f, M, DD, DD);
}

// Round 5
// 125.846 us; speedup vs baseline: 2.2458x; 1.8382x over previous
//
#include <hip/hip_runtime.h>
#include <hip/hip_bf16.h>

// Problem constants
#define BB 2
#define SS 2048
#define DD 1024
#define HH 16
#define DKK 64

typedef __attribute__((ext_vector_type(4))) float  f32x4;
typedef __attribute__((ext_vector_type(8))) short  s16x8;
typedef __attribute__((ext_vector_type(4))) short  s16x4;
typedef __attribute__((ext_vector_type(4))) float  fvec4;

__device__ __forceinline__ short f2bs(float f) {
    union { __hip_bfloat16 b; short s; } u;
    u.b = __float2bfloat16(f);
    return u.s;
}

__device__ __forceinline__ void gload_lds16(const short* g, short* l) {
    __builtin_amdgcn_global_load_lds((const __attribute__((address_space(1))) void*)g,
                                     (__attribute__((address_space(3))) void*)l, 16, 0, 0);
}

// ---------------------------------------------------------------------------
// fp32 -> bf16 convert, 7 tensors in one launch (blockIdx.y selects tensor)
// ---------------------------------------------------------------------------
__global__ __launch_bounds__(256) void cvt_all(
    const float* __restrict__ q,  const float* __restrict__ k,  const float* __restrict__ v,
    const float* __restrict__ wq, const float* __restrict__ wk, const float* __restrict__ wv,
    const float* __restrict__ wo,
    short* __restrict__ qo,  short* __restrict__ ko,  short* __restrict__ vo,
    short* __restrict__ wqo, short* __restrict__ wko, short* __restrict__ wvo,
    short* __restrict__ woo)
{
    const float* src; short* dst; int n;
    switch (blockIdx.y) {
        case 0: src = q;  dst = qo;  n = BB * SS * DD; break;
        case 1: src = k;  dst = ko;  n = BB * SS * DD; break;
        case 2: src = v;  dst = vo;  n = BB * SS * DD; break;
        case 3: src = wq; dst = wqo; n = DD * DD; break;
        case 4: src = wk; dst = wko; n = DD * DD; break;
        case 5: src = wv; dst = wvo; n = DD * DD; break;
        default: src = wo; dst = woo; n = DD * DD; break;
    }
    int i = (blockIdx.x * 256 + threadIdx.x) * 8;
    const int stride = gridDim.x * 256 * 8;
    for (; i < n; i += stride) {
        fvec4 a = *(const fvec4*)&src[i];
        fvec4 b = *(const fvec4*)&src[i + 4];
        s16x8 o;
        o[0] = f2bs(a[0]); o[1] = f2bs(a[1]); o[2] = f2bs(a[2]); o[3] = f2bs(a[3]);
        o[4] = f2bs(b[0]); o[5] = f2bs(b[1]); o[6] = f2bs(b[2]); o[7] = f2bs(b[3]);
        *(s16x8*)&dst[i] = o;
    }
}

// ---------------------------------------------------------------------------
// GEMM (NT), bf16 A and B: C[M,N] = (A[M,K] * Bw[N,K]^T + bias) * oscale
// m97 structure: global_load_lds(16B) staging, 2-barrier K-loop, BK=32.
// ---------------------------------------------------------------------------
template<int BN, bool OUTF32>
__global__ __launch_bounds__(256) void gemm_nt_bf16(
    const short* __restrict__ A0, const short* __restrict__ A1, const short* __restrict__ A2,
    const short* __restrict__ B0, const short* __restrict__ B1, const short* __restrict__ B2,
    const float* __restrict__ c0, const float* __restrict__ c1, const float* __restrict__ c2,
    void* __restrict__ O0, void* __restrict__ O1, void* __restrict__ O2,
    float os0, float os1, float os2, int M, int N, int K)
{
    const int z = blockIdx.z;
    const short* A    = z == 0 ? A0 : (z == 1 ? A1 : A2);
    const short* Bw   = z == 0 ? B0 : (z == 1 ? B1 : B2);
    const float* bias = z == 0 ? c0 : (z == 1 ? c1 : c2);
    void* Cp          = z == 0 ? O0 : (z == 1 ? O1 : O2);
    const float oscale = z == 0 ? os0 : (z == 1 ? os1 : os2);

    __shared__ short As[128][32];
    __shared__ short Bs[BN][32];

    const int tid  = threadIdx.x;
    const int lane = tid & 63;
    const int wid  = tid >> 6;
    const int r16  = lane & 15;
    const int g    = lane >> 4;
    const int m0   = blockIdx.y * 128;
    const int n0   = blockIdx.x * BN;
    constexpr int MR = (BN == 128) ? 4 : 2;
    constexpr int NR = 4;
    const int wr = (BN == 128) ? (wid >> 1) * 64 : wid * 32;
    const int wc = (BN == 128) ? (wid & 1) * 64 : 0;
    const int lrow = lane >> 2;          // 0..15, row within 16-row stripe
    const int lch  = (lane & 3) * 8;     // 8-elem col chunk

    f32x4 acc[MR][NR];
#pragma unroll
    for (int mi = 0; mi < MR; ++mi)
#pragma unroll
        for (int ni = 0; ni < NR; ++ni) acc[mi][ni] = (f32x4){0.f, 0.f, 0.f, 0.f};

    const int nk = K >> 5;
#pragma unroll 1
    for (int kt = 0; kt < nk; ++kt) {
        const int k0 = kt * 32;
        if (kt) __syncthreads();
        {
            const short* ga = &A[(size_t)(m0 + wid * 32 + lrow) * K + k0 + lch];
            gload_lds16(ga, &As[wid * 32][0]);
            gload_lds16(ga + (size_t)16 * K, &As[wid * 32 + 16][0]);
        }
        if constexpr (BN == 128) {
            const short* gb = &Bw[(size_t)(n0 + wid * 32 + lrow) * K + k0 + lch];
            gload_lds16(gb, &Bs[wid * 32][0]);
            gload_lds16(gb + (size_t)16 * K, &Bs[wid * 32 + 16][0]);
        } else {
            const short* gb = &Bw[(size_t)(n0 + wid * 16 + lrow) * K + k0 + lch];
            gload_lds16(gb, &Bs[wid * 16][0]);
        }
        __syncthreads();   // drains vmcnt

        s16x8 af[MR], bf[NR];
#pragma unroll
        for (int mi = 0; mi < MR; ++mi)
            af[mi] = *(const s16x8*)&As[wr + mi * 16 + r16][g * 8];
#pragma unroll
        for (int ni = 0; ni < NR; ++ni)
            bf[ni] = *(const s16x8*)&Bs[wc + ni * 16 + r16][g * 8];
#pragma unroll
        for (int mi = 0; mi < MR; ++mi)
#pragma unroll
            for (int ni = 0; ni < NR; ++ni)
                acc[mi][ni] = __builtin_amdgcn_mfma_f32_16x16x32_bf16(
                    af[mi], bf[ni], acc[mi][ni], 0, 0, 0);
    }

#pragma unroll
    for (int ni = 0; ni < NR; ++ni) {
        const int col = n0 + wc + ni * 16 + r16;
        const float bv = bias[col];
#pragma unroll
        for (int mi = 0; mi < MR; ++mi) {
#pragma unroll
            for (int r = 0; r < 4; ++r) {
                const int row = m0 + wr + mi * 16 + g * 4 + r;
                const float vv = (acc[mi][ni][r] + bv) * oscale;
                if constexpr (OUTF32)
                    ((float*)Cp)[(size_t)row * N + col] = vv;
                else
                    ((short*)Cp)[(size_t)row * N + col] = f2bs(vv);
            }
        }
    }
}

// ---------------------------------------------------------------------------
// Per-head V transpose: vp (head-major [bh][s][dk]) -> vT ([bh][dk][s])
// ---------------------------------------------------------------------------
__global__ __launch_bounds__(256) void mha_transpose_v(
    const short* __restrict__ vp, short* __restrict__ vT)
{
    const int st = blockIdx.x;
    const int bh = blockIdx.y;
    const short* src = vp + (size_t)bh * SS * DKK;
    short*       dst = vT + (size_t)bh * SS * DKK;
    const int tid = threadIdx.x;
#pragma unroll
    for (int i = 0; i < 2; ++i) {
        const int c  = tid + i * 256;   // 0..511
        const int dk = c >> 3;          // 0..63
        const int sc = c & 7;           // 0..7
        const int s0 = st * 64 + sc * 8;
        s16x8 v;
#pragma unroll
        for (int j = 0; j < 8; ++j) v[j] = src[(size_t)(s0 + j) * DKK + dk];
        *(s16x8*)&dst[(size_t)dk * SS + s0] = v;
    }
}

// ---------------------------------------------------------------------------
// Flash attention (causal), buggy-reshape head layout -- LDS-SHARED K/V.
// Diagnosis r4: per-wave register K/V frag loads = 16KB/wave/k-tile through
// the per-CU vector-memory port (~1.08 GB total, L2-hit) -> port-bandwidth
// bound, occupancy didn't help. Fix: stage K[64][64]+Vt[64][64] (16KB) into
// LDS ONCE per block per k-tile via global_load_lds (4x port-traffic cut).
// Block = one head x two 64-row q-groups (bx, 31-bx) -> 33 k-tiles/block,
// identical for all blocks; all 4 waves in a group share the same diag tile
// (no intra-block imbalance). Staging uses chunk^=(row&7) XOR swizzle applied
// to the GLOBAL source (LDS dest must be linear); ds_reads apply the same
// XOR -> even spread over all 8 bank-quads (bandwidth-bound, no hot bank).
// Grid (bh=32, bx=16): linear%8 = bh%8 pins each head's K/V to one XCD L2.
// ---------------------------------------------------------------------------
__global__ __launch_bounds__(256, 2) void mha_attn(
    const short* __restrict__ qp, const short* __restrict__ kp,
    const short* __restrict__ vT, short* __restrict__ ctx)
{
    __shared__ short Ks[64][64];     // [key][dk]   (chunk-swizzled)
    __shared__ short Vs[64][64];     // [dv][key]   (chunk-swizzled)
    __shared__ short P[4][16][72];   // per-wave P, padded rows

    const int tid  = threadIdx.x;
    const int wid  = tid >> 6;
    const int lane = tid & 63;
    const int r16  = lane & 15;
    const int g    = lane >> 4;

    const int bh  = blockIdx.x;   // 0..31 -> XCD = bh%8 (head pinned to XCD)
    const int bxp = blockIdx.y;   // 0..15
    const int b   = bh >> 4;
    const int h   = bh & 15;

    const short* Qh = qp + (size_t)bh * SS * DKK;
    const short* Kh = kp + (size_t)bh * SS * DKK;
    const short* Vh = vT + (size_t)bh * SS * DKK;   // [DK][S]

    // staging coords (per lane, fixed): 8 rows x 8 chunks per instr
    const int srow = lane >> 3;          // 0..7
    const int r0   = wid * 16;           // wave's 16-row stripe

#pragma unroll 1
    for (int t = 0; t < 2; ++t) {
        const int grp = t ? (31 - bxp) : bxp;     // 64-row q-group index
        const int qr0 = grp * 64 + wid * 16;
        const int nkt = grp + 1;

        const s16x8 qf0 = *(const s16x8*)&Qh[(size_t)(qr0 + r16) * DKK + g * 8];
        const s16x8 qf1 = *(const s16x8*)&Qh[(size_t)(qr0 + r16) * DKK + 32 + g * 8];

        f32x4 po[4];
#pragma unroll
        for (int i = 0; i < 4; ++i) po[i] = (f32x4){0.f, 0.f, 0.f, 0.f};
        float l_[4] = {0.f, 0.f, 0.f, 0.f};

#pragma unroll 1
        for (int j = 0; j < nkt; ++j) {
            const int k0 = j * 64;
            __syncthreads();   // protect Ks/Vs (and P across groups)
            // ---- stage K and Vt tiles (16KB), source-swizzled ----
            {
                const int rowA = r0 + srow;
                const int rowB = rowA + 8;
                const int cA = (((lane & 7) ^ (rowA & 7)) & 7) * 8;
                const int cB = (((lane & 7) ^ (rowB & 7)) & 7) * 8;
                gload_lds16(&Kh[(size_t)(k0 + rowA) * DKK + cA], &Ks[r0][0]);
                gload_lds16(&Kh[(size_t)(k0 + rowB) * DKK + cB], &Ks[r0 + 8][0]);
                gload_lds16(&Vh[(size_t)rowA * SS + k0 + cA], &Vs[r0][0]);
                gload_lds16(&Vh[(size_t)rowB * SS + k0 + cB], &Vs[r0 + 8][0]);
            }
            __syncthreads();   // drain vmcnt: tiles ready

            // ---- QK^T from LDS (swizzled reads) ----
            f32x4 sc[4];
            __builtin_amdgcn_s_setprio(1);
#pragma unroll
            for (int cg = 0; cg < 4; ++cg) {
                const int R  = cg * 16 + r16;
                const int sw = R & 7;
                const s16x8 kf0 = *(const s16x8*)&Ks[R][((g ^ sw) & 7) * 8];
                const s16x8 kf1 = *(const s16x8*)&Ks[R][(((4 + g) ^ sw) & 7) * 8];
                f32x4 tt = (f32x4){0.f, 0.f, 0.f, 0.f};
                tt = __builtin_amdgcn_mfma_f32_16x16x32_bf16(qf0, kf0, tt, 0, 0, 0);
                tt = __builtin_amdgcn_mfma_f32_16x16x32_bf16(qf1, kf1, tt, 0, 0, 0);
                sc[cg] = tt;
            }
            __builtin_amdgcn_s_setprio(0);

            // ---- causal mask (diag tile = last tile of the group) ----
            if (j == nkt - 1) {
#pragma unroll
                for (int cg = 0; cg < 4; ++cg)
#pragma unroll
                    for (int r = 0; r < 4; ++r)
                        if (k0 + cg * 16 + r16 > qr0 + g * 4 + r) sc[cg][r] = -1e9f;
            }
            // ---- softmax-lite: exp + per-lane partial sums + P write ----
#pragma unroll
            for (int cg = 0; cg < 4; ++cg)
#pragma unroll
                for (int r = 0; r < 4; ++r) {
                    const float p = __expf(sc[cg][r]);
                    l_[r] += p;
                    P[wid][g * 4 + r][cg * 16 + r16] = f2bs(p);
                }
            // same-wave write->read: compiler inserts lgkmcnt wait
            const s16x8 pf0 = *(const s16x8*)&P[wid][r16][g * 8];
            const s16x8 pf1 = *(const s16x8*)&P[wid][r16][32 + g * 8];

            // ---- PV from LDS Vt (swizzled reads) ----
            __builtin_amdgcn_s_setprio(1);
#pragma unroll
            for (int dg = 0; dg < 4; ++dg) {
                const int Rv = dg * 16 + r16;
                const int sw = Rv & 7;
                const s16x8 vf0 = *(const s16x8*)&Vs[Rv][((g ^ sw) & 7) * 8];
                const s16x8 vf1 = *(const s16x8*)&Vs[Rv][(((4 + g) ^ sw) & 7) * 8];
                po[dg] = __builtin_amdgcn_mfma_f32_16x16x32_bf16(pf0, vf0, po[dg], 0, 0, 0);
                po[dg] = __builtin_amdgcn_mfma_f32_16x16x32_bf16(pf1, vf1, po[dg], 0, 0, 0);
            }
            __builtin_amdgcn_s_setprio(0);
        }

        // ---- epilogue: reduce row sums across 16 lanes, normalize, store ----
#pragma unroll
        for (int r = 0; r < 4; ++r) {
#pragma unroll
            for (int off = 1; off < 16; off <<= 1)
                l_[r] += __shfl_xor(l_[r], off);
        }
#pragma unroll
        for (int dg = 0; dg < 4; ++dg)
#pragma unroll
            for (int r = 0; r < 4; ++r) {
                const int srw = qr0 + g * 4 + r;
                const float v = po[dg][r] * __builtin_amdgcn_rcpf(l_[r]);
                ctx[((size_t)(b * SS + srw)) * DD + h * 64 + dg * 16 + r16] = f2bs(v);
            }
    }
}

// ---------------------------------------------------------------------------
extern "C" void kernel_launch(void* const* d_in, const int* in_sizes, int n_in,
                              void* d_out, int out_size, void* d_ws, size_t ws_size,
                              hipStream_t stream) {
    const float* query = (const float*)d_in[0];
    const float* key   = (const float*)d_in[1];
    const float* value = (const float*)d_in[2];
    // d_in[3] = mask (causal tril) -- implemented analytically
    const float* Wq = (const float*)d_in[4];
    const float* bq = (const float*)d_in[5];
    const float* Wk = (const float*)d_in[6];
    const float* bk = (const float*)d_in[7];
    const float* Wv = (const float*)d_in[8];
    const float* bv = (const float*)d_in[9];
    const float* Wo = (const float*)d_in[10];
    const float* bo = (const float*)d_in[11];
    float* out = (float*)d_out;

    const size_t elems = (size_t)BB * SS * DD;   // 4M
    const size_t wel   = (size_t)DD * DD;        // 1M
    short* qx  = (short*)d_ws;        // bf16 inputs
    short* kx  = qx + elems;
    short* vx  = kx + elems;
    short* wqx = vx + elems;          // bf16 weights
    short* wkx = wqx + wel;
    short* wvx = wkx + wel;
    short* wox = wvx + wel;
    short* qp  = wox + wel;           // projections
    short* kp  = qp + elems;
    short* vp  = kp + elems;
    short* vT  = qx;                  // qx dead after QKV GEMM launch
    short* ctx = kx;                  // kx dead after QKV GEMM launch

    const int M = BB * SS;   // 4096

    // 1) convert everything to bf16
    cvt_all<<<dim3(1024, 7), 256, 0, stream>>>(query, key, value, Wq, Wk, Wv, Wo,
                                               qx, kx, vx, wqx, wkx, wvx, wox);
    // 2) fused Q/K/V projections; 1/sqrt(DK) folded into Q
    gemm_nt_bf16<128, false><<<dim3(DD / 128, M / 128, 3), 256, 0, stream>>>(
        qx, kx, vx, wqx, wkx, wvx, bq, bk, bv, qp, kp, vp,
        0.125f, 1.0f, 1.0f, M, DD, DD);
    // 3) V transpose per head
    mha_transpose_v<<<dim3(SS / 64, BB * HH), 256, 0, stream>>>(vp, vT);
    // 4) attention (512 blocks, LDS-shared K/V)
    mha_attn<<<dim3(BB * HH, 16), 256, 0, stream>>>(qp, kp, vT, ctx);
    // 5) output projection
    gemm_nt_bf16<64, true><<<dim3(DD / 64, M / 128, 1), 256, 0, stream>>>(
        ctx, ctx, ctx, wox, wox, wox, bo, bo, bo, out, out, out,
        1.0f, 1.0f, 1.0f, M, DD, DD);
}